// Round 3
// baseline (607.853 us; speedup 1.0000x reference)
//
#include <hip/hip_runtime.h>

typedef short bf16x8 __attribute__((ext_vector_type(8)));
typedef float f32x4  __attribute__((ext_vector_type(4)));
typedef unsigned u32x2 __attribute__((ext_vector_type(2)));

#define MFMA(A, B, C) __builtin_amdgcn_mfma_f32_16x16x32_bf16(A, B, C, 0, 0, 0)

__device__ __forceinline__ short f2b(float f) {
  union { float f; unsigned u; } v; v.f = f;
  unsigned r = v.u + 0x7fffu + ((v.u >> 16) & 1u);   // RNE float->bf16
  return (short)(r >> 16);
}
// packed RNE f32x2 -> bf16x2 (same rounding as f2b, 1 instr per 2 values)
__device__ __forceinline__ unsigned pkbf(float a, float b) {
  unsigned r; asm("v_cvt_pk_bf16_f32 %0, %1, %2" : "=v"(r) : "v"(a), "v"(b));
  return r;
}

#define NTOK 49
#define CDIM 128
#define SCALE 0.17677669529663687f   // 32^-0.5

// ---------------- LDS map (bytes), total 32256 ----------------
// region X [0,13328):
//    t0: msk 49 rows x stride 52 f32 (10192) + bia 169*4 f32 @10192  [freed at B3]
//    t1: os 49x136 bf16 (attention output)   [B3..end]
// region V [13328,32256): 4 per-wave slots x 4608 B (wave == head, fully private):
//    per slot, time-shared: q-scratch 49x40 -> k-scratch 49x40 -> v^T 32x72
//    (scratch reads touch rows 49..63 = garbage overrun into the next slot; those
//     rows are padded queries/keys -> masked or discarded. v^T pad tokens 49..63
//     are ZEROED at store: PV contracts over keys; 0*NaN=NaN would leak.)
// x is NOT staged: all 4 waves load identical fragments straight from global
// (L1-resident, 25KB/block) -> kills 2 barriers + all xs LDS traffic.
#define XS_STR 136
#define QK_STR 40
#define VT_STR 72
#define MSK_STR 52
#define VOFF    13328
#define SLOT_B  4608
#define BIA_OFF 10192
#define LDS_TOTAL 32256

extern "C" __global__ void winattn_prep(const float* __restrict__ qw,
                                        const float* __restrict__ pw,
                                        short* __restrict__ wq, short* __restrict__ wp) {
  const int i = blockIdx.x * 256 + threadIdx.x;
  if (i < 384 * 128) wq[i] = f2b(qw[i]);
  if (i < 128 * 128) wp[i] = f2b(pw[i]);
}

extern "C" __global__ void __launch_bounds__(256, 4)
winattn_main(const float* __restrict__ x, const float* __restrict__ mask,
             const float* __restrict__ qkv_b, const float* __restrict__ proj_b,
             const float* __restrict__ bias_table,
             const short* __restrict__ wq, const short* __restrict__ wp,
             float* __restrict__ out)
{
  extern __shared__ char lds[];
  float* msk = (float*)lds;
  float* bia = (float*)(lds + BIA_OFF);
  short* os  = (short*)lds;

  const int tid  = threadIdx.x;
  const int blk  = blockIdx.x;
  const int wi   = blk & 63;          // window-mask index: b % nW
  const int h    = tid >> 6;          // wave == head
  const int lane = tid & 63;
  const int m    = lane & 15;
  const int quad = lane >> 4;

  short* slot = (short*)(lds + VOFF + h * SLOT_B);   // wave-private

  // ---------------- mask+bias global loads issued FIRST (oldest in vmcnt queue)
  float mreg[10], breg[3];
  {
    const float* mw = mask + (size_t)wi * (NTOK * NTOK);
    #pragma unroll
    for (int it = 0; it < 10; ++it) {
      int i = tid + it * 256;
      mreg[it] = (i < NTOK * NTOK) ? mw[i] : 0.f;
    }
    #pragma unroll
    for (int it = 0; it < 3; ++it) {
      int i = tid + it * 256;
      breg[it] = (i < 169 * 4) ? bias_table[i] : 0.f;
    }
  }

  // ---------------- x fragments direct from global (no LDS stage, no barrier)
  // frag (mt,kk): lane (m,quad) holds x[row][kk*32+quad*8 .. +7] as bf16.
  // pad rows (>=49) clamp to row 48: finite real data, later masked/zeroed.
  bf16x8 ax[4][4];
  {
    const float* xb = x + (size_t)blk * (NTOK * CDIM);
    #pragma unroll
    for (int mt = 0; mt < 4; ++mt) {
      const int r0 = mt * 16 + m;
      const int row = (r0 < NTOK) ? r0 : (NTOK - 1);
      const float* xr = xb + row * CDIM + quad * 8;
      #pragma unroll
      for (int kk = 0; kk < 4; ++kk) {
        float4 f0 = *(const float4*)(xr + kk * 32);
        float4 f1 = *(const float4*)(xr + kk * 32 + 4);
        union { unsigned u[4]; bf16x8 v; } t;
        t.u[0] = pkbf(f0.x, f0.y); t.u[1] = pkbf(f0.z, f0.w);
        t.u[2] = pkbf(f1.x, f1.y); t.u[3] = pkbf(f1.z, f1.w);
        ax[mt][kk] = t.v;
      }
    }
  }

  // ---------------- stage mask (stride 52, float4-readable) + bias into region X
  #pragma unroll
  for (int it = 0; it < 10; ++it) {
    int i = tid + it * 256;
    if (i < NTOK * NTOK) {
      int row = (unsigned)i / 49u, col = i - row * 49;
      msk[row * MSK_STR + col] = mreg[it];
    }
  }
  #pragma unroll
  for (int it = 0; it < 3; ++it) {
    int i = tid + it * 256;
    if (i < 169 * 4) bia[i] = breg[it];
  }

  // ---------------- phase A: head-aligned qkv tiles (q0 q1 k0 k1 v0 v1)
  // scratch col swizzle: col ^ ((row&8)?8:0) -> store conflicts 4-way -> 2-way
  bf16x8 bq[4], ak[4];
  #pragma unroll
  for (int t = 0; t < 6; ++t) {
    const int kind = t >> 1, sub = t & 1;
    const int n = kind * 128 + h * 32 + sub * 16 + m;
    const short* wr = wq + n * CDIM + quad * 8;
    bf16x8 bw[4];
    #pragma unroll
    for (int kk = 0; kk < 4; ++kk) bw[kk] = *(const bf16x8*)(wr + kk * 32);
    f32x4 acc[4] = {};
    __builtin_amdgcn_s_setprio(1);
    #pragma unroll
    for (int kk = 0; kk < 4; ++kk)
      #pragma unroll
      for (int mt = 0; mt < 4; ++mt)
        acc[mt] = MFMA(ax[mt][kk], bw[kk], acc[mt]);
    __builtin_amdgcn_s_setprio(0);
    const float bb = qkv_b[n];
    if (kind < 2) {
      const int cs = (sub * 16 + m) ^ ((quad >= 2) ? 8 : 0);  // row&8 == (quad>=2)*8
      #pragma unroll
      for (int mt = 0; mt < 4; ++mt)
        #pragma unroll
        for (int j = 0; j < 2; ++j) {
          const int row = mt * 16 + quad * 4 + 2 * j;
          unsigned u = pkbf(acc[mt][2 * j] + bb, acc[mt][2 * j + 1] + bb);
          if (row < NTOK)     slot[row * QK_STR + cs] = (short)u;
          if (row + 1 < NTOK) slot[(row + 1) * QK_STR + cs] = (short)(u >> 16);
        }
    } else {
      // v stored transposed in slot: [channel 0..31][token 0..63], pairs packed.
      // PAD TOKENS (>=49) MUST BE 0.0 (PV contracts over all 64 keys).
      const int c = sub * 16 + m;
      #pragma unroll
      for (int mt = 0; mt < 4; ++mt) {
        const int t0 = mt * 16 + quad * 4;
        const float e0 = (t0 + 0 < NTOK) ? acc[mt][0] + bb : 0.f;
        const float e1 = (t0 + 1 < NTOK) ? acc[mt][1] + bb : 0.f;
        const float e2 = (t0 + 2 < NTOK) ? acc[mt][2] + bb : 0.f;
        const float e3 = (t0 + 3 < NTOK) ? acc[mt][3] + bb : 0.f;
        u32x2 w;
        w.x = pkbf(e0, e1);
        w.y = pkbf(e2, e3);
        *(u32x2*)&slot[c * VT_STR + t0] = w;
      }
    }
    if (t == 1) {          // q done -> B-fragments (queries); same-wave DS is FIFO
      #pragma unroll
      for (int qt = 0; qt < 4; ++qt)
        bq[qt] = *(const bf16x8*)&slot[(qt * 16 + m) * QK_STR + ((quad * 8) ^ (m & 8))];
    }
    if (t == 3) {          // k done -> A-fragments (keys)
      #pragma unroll
      for (int kt = 0; kt < 4; ++kt)
        ak[kt] = *(const bf16x8*)&slot[(kt * 16 + m) * QK_STR + ((quad * 8) ^ (m & 8))];
    }
  }

  // ---------------- phase B: S^T = K Q^T  (rows=keys, cols=queries), K=32
  f32x4 st[4][4] = {};
  __builtin_amdgcn_s_setprio(1);
  #pragma unroll
  for (int kt = 0; kt < 4; ++kt)
    #pragma unroll
    for (int qt = 0; qt < 4; ++qt)
      st[kt][qt] = MFMA(ak[kt], bq[qt], st[kt][qt]);
  __builtin_amdgcn_s_setprio(0);

  __syncthreads();                                   // Bm: msk/bia visible

  // ---------------- softmax over keys (column-wise on S^T): quad-local reduce
  int kc[13];
  #pragma unroll
  for (int i = 0; i < 13; ++i) {                     // kt<3 all r, plus (kt=3,r=0)
    int kt = i >> 2, r = i & 3;
    int key = kt * 16 + quad * 4 + r;
    int ch = (unsigned)key / 7u;
    kc[i] = ch * 13 + (key - ch * 7);
  }
  float rinv[4];
  #pragma unroll
  for (int qt = 0; qt < 4; ++qt) {
    const int query = qt * 16 + m;
    const int rh = (unsigned)query / 7u;
    const int qcode = rh * 13 + (query - rh * 7) + 84;   // idx = qcode - kcode
    float sv[13];
    #pragma unroll
    for (int kt = 0; kt < 3; ++kt) {
      const float4 mk = *(const float4*)&msk[query * MSK_STR + kt * 16 + quad * 4];
      #pragma unroll
      for (int r = 0; r < 4; ++r) {
        const float b = bia[(qcode - kc[kt * 4 + r]) * 4 + h];
        sv[kt * 4 + r] = st[kt][qt][r] * SCALE + ((const float*)&mk)[r] + b;
      }
    }
    {   // kt=3: only key 48 (quad==0, r==0) is real
      const float mk3 = msk[query * MSK_STR + 48];
      const float b3 = bia[(qcode - kc[12]) * 4 + h];
      float s = st[3][qt][0] * SCALE + mk3 + b3;
      sv[12] = (quad == 0) ? s : -1e30f;
    }
    float mx = sv[0];
    #pragma unroll
    for (int i = 1; i < 13; ++i) mx = fmaxf(mx, sv[i]);
    mx = fmaxf(mx, __shfl_xor(mx, 16));
    mx = fmaxf(mx, __shfl_xor(mx, 32));
    float sum = 0.f;
    #pragma unroll
    for (int i = 0; i < 13; ++i) {
      const float p = __expf(sv[i] - mx);             // unnormalized, 1/sum into O
      sum += p;
      st[i >> 2][qt][i & 3] = p;
    }
    st[3][qt][1] = 0.f; st[3][qt][2] = 0.f; st[3][qt][3] = 0.f;  // pad keys
    sum += __shfl_xor(sum, 16);
    sum += __shfl_xor(sum, 32);
    rinv[qt] = 1.f / sum;
  }

  // ---------------- phase C: O^T = V^T P^T, P^T B-frags via ds_bpermute dance
  bf16x8 av[2][2];
  #pragma unroll
  for (int ct = 0; ct < 2; ++ct)
    #pragma unroll
    for (int k2 = 0; k2 < 2; ++k2)
      av[ct][k2] = *(const bf16x8*)&slot[(ct * 16 + m) * VT_STR + k2 * 32 + quad * 8];

  // fixed 64-lane permutation addresses (byte = lane*4)
  const int A0  = (lane ^ ((quad & 1) ? 48 : 0))  << 2;
  const int B0  = (lane ^ ((quad & 1) ? 16 : 32)) << 2;
  const int A2  = (lane ^ ((quad & 1) ? 32 : 16)) << 2;
  const int B2g = (lane ^ ((quad & 1) ? 0 : 48))  << 2;
  const bool qlo = quad < 2;

  f32x4 oacc[2][4] = {};
  #pragma unroll
  for (int qt = 0; qt < 4; ++qt) {
    #pragma unroll
    for (int k2 = 0; k2 < 2; ++k2) {
      const unsigned elo = pkbf(st[2 * k2][qt][0], st[2 * k2][qt][1]);
      const unsigned ehi = pkbf(st[2 * k2][qt][2], st[2 * k2][qt][3]);
      const unsigned olo = pkbf(st[2 * k2 + 1][qt][0], st[2 * k2 + 1][qt][1]);
      const unsigned ohi = pkbf(st[2 * k2 + 1][qt][2], st[2 * k2 + 1][qt][3]);
      // bpermutes unconditional (convergent, full exec), then per-lane select
      const unsigned p0e = __builtin_amdgcn_ds_bpermute(A0,  (int)elo);
      const unsigned p0o = __builtin_amdgcn_ds_bpermute(B0,  (int)olo);
      const unsigned p1e = __builtin_amdgcn_ds_bpermute(A0,  (int)ehi);
      const unsigned p1o = __builtin_amdgcn_ds_bpermute(B0,  (int)ohi);
      const unsigned p2e = __builtin_amdgcn_ds_bpermute(A2,  (int)elo);
      const unsigned p2o = __builtin_amdgcn_ds_bpermute(B2g, (int)olo);
      const unsigned p3e = __builtin_amdgcn_ds_bpermute(A2,  (int)ehi);
      const unsigned p3o = __builtin_amdgcn_ds_bpermute(B2g, (int)ohi);
      union { unsigned u[4]; bf16x8 v; } pb;
      pb.u[0] = qlo ? p0e : p0o;
      pb.u[1] = qlo ? p1e : p1o;
      pb.u[2] = qlo ? p2e : p2o;
      pb.u[3] = qlo ? p3e : p3o;
      __builtin_amdgcn_s_setprio(1);
      #pragma unroll
      for (int ct = 0; ct < 2; ++ct)
        oacc[ct][qt] = MFMA(av[ct][k2], pb.v, oacc[ct][qt]);
      __builtin_amdgcn_s_setprio(0);
    }
  }

  __syncthreads();     // B3: all mask/bias reads done -> os may overwrite region X
  #pragma unroll
  for (int ct = 0; ct < 2; ++ct)
    #pragma unroll
    for (int qt = 0; qt < 4; ++qt) {
      const int query = qt * 16 + m;
      if (query < NTOK) {
        u32x2 w;
        w.x = pkbf(oacc[ct][qt][0] * rinv[qt], oacc[ct][qt][1] * rinv[qt]);
        w.y = pkbf(oacc[ct][qt][2] * rinv[qt], oacc[ct][qt][3] * rinv[qt]);
        *(u32x2*)&os[query * XS_STR + h * 32 + ct * 16 + quad * 4] = w;
      }
    }
  __syncthreads();                                   // B4: os ready

  // ---------------- phase D: out = O @ proj_w^T + proj_b, fp32 store
  {
    bf16x8 ao[4][4];
    #pragma unroll
    for (int mt = 0; mt < 4; ++mt)
      #pragma unroll
      for (int kk = 0; kk < 4; ++kk)
        ao[mt][kk] = *(const bf16x8*)&os[(mt * 16 + m) * XS_STR + kk * 32 + quad * 8];
    float* outb = out + (size_t)blk * (NTOK * CDIM);
    #pragma unroll
    for (int t = 0; t < 2; ++t) {
      const int n = (h * 2 + t) * 16 + m;
      const short* wr = wp + n * CDIM + quad * 8;
      bf16x8 bw[4];
      #pragma unroll
      for (int kk = 0; kk < 4; ++kk) bw[kk] = *(const bf16x8*)(wr + kk * 32);
      f32x4 acc[4] = {};
      __builtin_amdgcn_s_setprio(1);
      #pragma unroll
      for (int kk = 0; kk < 4; ++kk)
        #pragma unroll
        for (int mt = 0; mt < 4; ++mt)
          acc[mt] = MFMA(ao[mt][kk], bw[kk], acc[mt]);
      __builtin_amdgcn_s_setprio(0);
      const float pb2 = proj_b[n];
      #pragma unroll
      for (int mt = 0; mt < 4; ++mt)
        #pragma unroll
        for (int r = 0; r < 4; ++r) {
          const int row = mt * 16 + quad * 4 + r;
          if (row < NTOK) outb[row * CDIM + n] = acc[mt][r] + pb2;
        }
    }
  }
}

extern "C" void kernel_launch(void* const* d_in, const int* in_sizes, int n_in,
                              void* d_out, int out_size, void* d_ws, size_t ws_size,
                              hipStream_t stream)
{
  const float* x          = (const float*)d_in[0];
  const float* mask       = (const float*)d_in[1];
  const float* qkv_w      = (const float*)d_in[2];
  const float* qkv_b      = (const float*)d_in[3];
  const float* proj_w     = (const float*)d_in[4];
  const float* proj_b     = (const float*)d_in[5];
  const float* bias_table = (const float*)d_in[6];

  short* wq = (short*)d_ws;              // 384*128 bf16
  short* wp = wq + 384 * 128;            // 128*128 bf16

  winattn_prep<<<192, 256, 0, stream>>>(qkv_w, proj_w, wq, wp);
  winattn_main<<<8192, 256, LDS_TOTAL, stream>>>(x, mask, qkv_b, proj_b, bias_table,
                                                 wq, wp, (float*)d_out);
}

// Round 4
// 578.175 us; speedup vs baseline: 1.0513x; 1.0513x over previous
//
#include <hip/hip_runtime.h>

typedef short bf16x8 __attribute__((ext_vector_type(8)));
typedef float f32x4  __attribute__((ext_vector_type(4)));
typedef unsigned u32x2 __attribute__((ext_vector_type(2)));

#define MFMA(A, B, C) __builtin_amdgcn_mfma_f32_16x16x32_bf16(A, B, C, 0, 0, 0)

__device__ __forceinline__ short f2b(float f) {
  union { float f; unsigned u; } v; v.f = f;
  unsigned r = v.u + 0x7fffu + ((v.u >> 16) & 1u);   // RNE float->bf16
  return (short)(r >> 16);
}
// packed RNE f32x2 -> bf16x2 (same rounding as f2b, 1 instr per 2 values)
__device__ __forceinline__ unsigned pkbf(float a, float b) {
  unsigned r; asm("v_cvt_pk_bf16_f32 %0, %1, %2" : "=v"(r) : "v"(a), "v"(b));
  return r;
}

#define NTOK 49
#define CDIM 128
#define SCALE 0.17677669529663687f   // 32^-0.5

// ---------------- LDS map (bytes), total 32256 ----------------
// region X [0,13328):
//    t0: xs 49x136 bf16 (x staged)             [freed at B2]
//    t1: msk 49 rows x stride 52 f32 (10192) + bia PER-HEAD 4x176 f32 @10192
//        (2816B; per-head contiguous kills the 8-way bank conflict of the
//         old [idx][h] stride-16B layout)                      [freed at B3]
//    t2: os 49x136 bf16 (attention output)     [B3..end]
// region V [13328,32256): 4 per-wave slots x 4608 B (wave == head, private):
//    per slot, time-shared: q-scratch 49x40 -> k-scratch 49x40 -> v^T 32x72
//    (v^T pad tokens 49..63 ZEROED at store: PV contracts over keys; 0*NaN leak)
// NOTE: occupancy is register-bound (~4 blocks/CU, VGPR 64 + AGPRs), not LDS.
#define XS_STR 136
#define QK_STR 40
#define VT_STR 72
#define MSK_STR 52
#define VOFF    13328
#define SLOT_B  4608
#define BIA_OFF 10192
#define BIA_STR 176
#define LDS_TOTAL 32256

extern "C" __global__ void winattn_prep(const float* __restrict__ qw,
                                        const float* __restrict__ pw,
                                        short* __restrict__ wq, short* __restrict__ wp) {
  const int i = blockIdx.x * 256 + threadIdx.x;
  if (i < 384 * 128) wq[i] = f2b(qw[i]);
  if (i < 128 * 128) wp[i] = f2b(pw[i]);
}

extern "C" __global__ void __launch_bounds__(256, 4)
winattn_main(const float* __restrict__ x, const float* __restrict__ mask,
             const float* __restrict__ qkv_b, const float* __restrict__ proj_b,
             const float* __restrict__ bias_table,
             const short* __restrict__ wq, const short* __restrict__ wp,
             float* __restrict__ out)
{
  extern __shared__ char lds[];
  short* xs  = (short*)lds;
  float* msk = (float*)lds;
  float* bia = (float*)(lds + BIA_OFF);
  short* os  = (short*)lds;

  const int tid  = threadIdx.x;
  const int blk  = blockIdx.x;
  const int wi   = blk & 63;          // window-mask index: b % nW
  const int h    = tid >> 6;          // wave == head
  const int lane = tid & 63;
  const int m    = lane & 15;
  const int quad = lane >> 4;

  short* slot = (short*)(lds + VOFF + h * SLOT_B);   // wave-private

  // ---------------- stage x -> bf16 LDS (stride 136)
  {
    const float4* xg = (const float4*)(x + (size_t)blk * (NTOK * CDIM));
    #pragma unroll
    for (int it = 0; it < 7; ++it) {
      int i = tid + it * 256;
      if (i < NTOK * 32) {
        float4 v = xg[i];
        int row = i >> 5, c4 = (i & 31) << 2;
        u32x2 w; w.x = pkbf(v.x, v.y); w.y = pkbf(v.z, v.w);
        *(u32x2*)&xs[row * XS_STR + c4] = w;
      }
    }
  }
  // mask+bias global loads to registers now (latency hides under barriers/phase A)
  float mreg[10], breg[3];
  {
    const float* mw = mask + (size_t)wi * (NTOK * NTOK);
    #pragma unroll
    for (int it = 0; it < 10; ++it) {
      int i = tid + it * 256;
      mreg[it] = (i < NTOK * NTOK) ? mw[i] : 0.f;
    }
    #pragma unroll
    for (int it = 0; it < 3; ++it) {
      int i = tid + it * 256;
      breg[it] = (i < 169 * 4) ? bias_table[i] : 0.f;
    }
  }
  __syncthreads();                                   // B1: xs ready

  // shared A-fragments of the QKV GEMM (x tile), all waves identical
  bf16x8 ax[4][4];
  #pragma unroll
  for (int mt = 0; mt < 4; ++mt)
    #pragma unroll
    for (int kk = 0; kk < 4; ++kk)
      ax[mt][kk] = *(const bf16x8*)&xs[(mt * 16 + m) * XS_STR + kk * 32 + quad * 8];
  __syncthreads();                                   // B2: xs region free

  // mask (stride 52, float4-readable) + bias (PER-HEAD rows) into region X
  #pragma unroll
  for (int it = 0; it < 10; ++it) {
    int i = tid + it * 256;
    if (i < NTOK * NTOK) {
      int row = (unsigned)i / 49u, col = i - row * 49;
      msk[row * MSK_STR + col] = mreg[it];
    }
  }
  #pragma unroll
  for (int it = 0; it < 3; ++it) {
    int i = tid + it * 256;
    if (i < 169 * 4) bia[(i & 3) * BIA_STR + (i >> 2)] = breg[it];
  }

  // ---------------- phase A: head-aligned qkv tiles (q0 q1 k0 k1 v0 v1)
  // scratch col swizzle: col ^ ((row&8)?8:0) -> store conflicts 4-way -> 2-way
  bf16x8 bq[4], ak[4];
  #pragma unroll
  for (int t = 0; t < 6; ++t) {
    const int kind = t >> 1, sub = t & 1;
    const int n = kind * 128 + h * 32 + sub * 16 + m;
    const short* wr = wq + n * CDIM + quad * 8;
    bf16x8 bw[4];
    #pragma unroll
    for (int kk = 0; kk < 4; ++kk) bw[kk] = *(const bf16x8*)(wr + kk * 32);
    f32x4 acc[4] = {};
    __builtin_amdgcn_s_setprio(1);
    #pragma unroll
    for (int kk = 0; kk < 4; ++kk)
      #pragma unroll
      for (int mt = 0; mt < 4; ++mt)
        acc[mt] = MFMA(ax[mt][kk], bw[kk], acc[mt]);
    __builtin_amdgcn_s_setprio(0);
    const float bb = qkv_b[n];
    if (kind < 2) {
      const int cs = (sub * 16 + m) ^ ((quad >= 2) ? 8 : 0);  // row&8 == (quad>=2)*8
      #pragma unroll
      for (int mt = 0; mt < 4; ++mt)
        #pragma unroll
        for (int j = 0; j < 2; ++j) {
          const int row = mt * 16 + quad * 4 + 2 * j;
          unsigned u = pkbf(acc[mt][2 * j] + bb, acc[mt][2 * j + 1] + bb);
          if (row < NTOK)     slot[row * QK_STR + cs] = (short)u;
          if (row + 1 < NTOK) slot[(row + 1) * QK_STR + cs] = (short)(u >> 16);
        }
    } else {
      // v stored transposed in slot: [channel 0..31][token 0..63], pairs packed.
      // PAD TOKENS (>=49) MUST BE 0.0 (PV contracts over all 64 keys).
      const int c = sub * 16 + m;
      #pragma unroll
      for (int mt = 0; mt < 4; ++mt) {
        const int t0 = mt * 16 + quad * 4;
        const float e0 = (t0 + 0 < NTOK) ? acc[mt][0] + bb : 0.f;
        const float e1 = (t0 + 1 < NTOK) ? acc[mt][1] + bb : 0.f;
        const float e2 = (t0 + 2 < NTOK) ? acc[mt][2] + bb : 0.f;
        const float e3 = (t0 + 3 < NTOK) ? acc[mt][3] + bb : 0.f;
        u32x2 w;
        w.x = pkbf(e0, e1);
        w.y = pkbf(e2, e3);
        *(u32x2*)&slot[c * VT_STR + t0] = w;
      }
    }
    if (t == 1) {          // q done -> B-fragments (queries); same-wave DS is FIFO
      #pragma unroll
      for (int qt = 0; qt < 4; ++qt)
        bq[qt] = *(const bf16x8*)&slot[(qt * 16 + m) * QK_STR + ((quad * 8) ^ (m & 8))];
    }
    if (t == 3) {          // k done -> A-fragments (keys)
      #pragma unroll
      for (int kt = 0; kt < 4; ++kt)
        ak[kt] = *(const bf16x8*)&slot[(kt * 16 + m) * QK_STR + ((quad * 8) ^ (m & 8))];
    }
  }

  // ---------------- phase B: S^T = K Q^T  (rows=keys, cols=queries), K=32
  f32x4 st[4][4] = {};
  __builtin_amdgcn_s_setprio(1);
  #pragma unroll
  for (int kt = 0; kt < 4; ++kt)
    #pragma unroll
    for (int qt = 0; qt < 4; ++qt)
      st[kt][qt] = MFMA(ak[kt], bq[qt], st[kt][qt]);
  __builtin_amdgcn_s_setprio(0);

  __syncthreads();                                   // Bm: msk/bia visible

  // ---------------- softmax over keys (column-wise on S^T): quad-local reduce
  int kc[13];
  #pragma unroll
  for (int i = 0; i < 13; ++i) {                     // kt<3 all r, plus (kt=3,r=0)
    int kt = i >> 2, r = i & 3;
    int key = kt * 16 + quad * 4 + r;
    int ch = (unsigned)key / 7u;
    kc[i] = ch * 13 + (key - ch * 7);
  }
  const float* biah = bia + h * BIA_STR;
  float rinv[4];
  #pragma unroll
  for (int qt = 0; qt < 4; ++qt) {
    const int query = qt * 16 + m;
    const int rh = (unsigned)query / 7u;
    const int qcode = rh * 13 + (query - rh * 7) + 84;   // idx = qcode - kcode
    float sv[13];
    #pragma unroll
    for (int kt = 0; kt < 3; ++kt) {
      const float4 mk = *(const float4*)&msk[query * MSK_STR + kt * 16 + quad * 4];
      #pragma unroll
      for (int r = 0; r < 4; ++r) {
        const float b = biah[qcode - kc[kt * 4 + r]];
        sv[kt * 4 + r] = st[kt][qt][r] * SCALE + ((const float*)&mk)[r] + b;
      }
    }
    {   // kt=3: only key 48 (quad==0, r==0) is real
      const float mk3 = msk[query * MSK_STR + 48];
      const float b3 = biah[qcode - kc[12]];
      float s = st[3][qt][0] * SCALE + mk3 + b3;
      sv[12] = (quad == 0) ? s : -1e30f;
    }
    float mx = sv[0];
    #pragma unroll
    for (int i = 1; i < 13; ++i) mx = fmaxf(mx, sv[i]);
    mx = fmaxf(mx, __shfl_xor(mx, 16));
    mx = fmaxf(mx, __shfl_xor(mx, 32));
    float sum = 0.f;
    #pragma unroll
    for (int i = 0; i < 13; ++i) {
      const float p = __expf(sv[i] - mx);             // unnormalized, 1/sum into O
      sum += p;
      st[i >> 2][qt][i & 3] = p;
    }
    st[3][qt][1] = 0.f; st[3][qt][2] = 0.f; st[3][qt][3] = 0.f;  // pad keys
    sum += __shfl_xor(sum, 16);
    sum += __shfl_xor(sum, 32);
    rinv[qt] = 1.f / sum;
  }

  // ---------------- phase C: O^T = V^T P^T, P^T B-frags via ds_bpermute dance
  bf16x8 av[2][2];
  #pragma unroll
  for (int ct = 0; ct < 2; ++ct)
    #pragma unroll
    for (int k2 = 0; k2 < 2; ++k2)
      av[ct][k2] = *(const bf16x8*)&slot[(ct * 16 + m) * VT_STR + k2 * 32 + quad * 8];

  // fixed 64-lane permutation addresses (byte = lane*4)
  const int A0  = (lane ^ ((quad & 1) ? 48 : 0))  << 2;
  const int B0  = (lane ^ ((quad & 1) ? 16 : 32)) << 2;
  const int A2  = (lane ^ ((quad & 1) ? 32 : 16)) << 2;
  const int B2g = (lane ^ ((quad & 1) ? 0 : 48))  << 2;
  const bool qlo = quad < 2;

  f32x4 oacc[2][4] = {};
  #pragma unroll
  for (int qt = 0; qt < 4; ++qt) {
    #pragma unroll
    for (int k2 = 0; k2 < 2; ++k2) {
      const unsigned elo = pkbf(st[2 * k2][qt][0], st[2 * k2][qt][1]);
      const unsigned ehi = pkbf(st[2 * k2][qt][2], st[2 * k2][qt][3]);
      const unsigned olo = pkbf(st[2 * k2 + 1][qt][0], st[2 * k2 + 1][qt][1]);
      const unsigned ohi = pkbf(st[2 * k2 + 1][qt][2], st[2 * k2 + 1][qt][3]);
      // bpermutes unconditional (convergent, full exec), then per-lane select
      const unsigned p0e = __builtin_amdgcn_ds_bpermute(A0,  (int)elo);
      const unsigned p0o = __builtin_amdgcn_ds_bpermute(B0,  (int)olo);
      const unsigned p1e = __builtin_amdgcn_ds_bpermute(A0,  (int)ehi);
      const unsigned p1o = __builtin_amdgcn_ds_bpermute(B0,  (int)ohi);
      const unsigned p2e = __builtin_amdgcn_ds_bpermute(A2,  (int)elo);
      const unsigned p2o = __builtin_amdgcn_ds_bpermute(B2g, (int)olo);
      const unsigned p3e = __builtin_amdgcn_ds_bpermute(A2,  (int)ehi);
      const unsigned p3o = __builtin_amdgcn_ds_bpermute(B2g, (int)ohi);
      union { unsigned u[4]; bf16x8 v; } pb;
      pb.u[0] = qlo ? p0e : p0o;
      pb.u[1] = qlo ? p1e : p1o;
      pb.u[2] = qlo ? p2e : p2o;
      pb.u[3] = qlo ? p3e : p3o;
      __builtin_amdgcn_s_setprio(1);
      #pragma unroll
      for (int ct = 0; ct < 2; ++ct)
        oacc[ct][qt] = MFMA(av[ct][k2], pb.v, oacc[ct][qt]);
      __builtin_amdgcn_s_setprio(0);
    }
  }

  __syncthreads();     // B3: all mask/bias reads done -> os may overwrite region X
  #pragma unroll
  for (int ct = 0; ct < 2; ++ct)
    #pragma unroll
    for (int qt = 0; qt < 4; ++qt) {
      const int query = qt * 16 + m;
      if (query < NTOK) {
        u32x2 w;
        w.x = pkbf(oacc[ct][qt][0] * rinv[qt], oacc[ct][qt][1] * rinv[qt]);
        w.y = pkbf(oacc[ct][qt][2] * rinv[qt], oacc[ct][qt][3] * rinv[qt]);
        *(u32x2*)&os[query * XS_STR + h * 32 + ct * 16 + quad * 4] = w;
      }
    }
  __syncthreads();                                   // B4: os ready

  // ---------------- phase D: out = O @ proj_w^T + proj_b, fp32 store
  // Both n-tiles computed FIRST, stores interleaved back-to-back per row so the
  // two 64B halves of each 128B line merge in L2 (fixes 2.37x WRITE_SIZE).
  {
    bf16x8 ao[4][4];
    #pragma unroll
    for (int mt = 0; mt < 4; ++mt)
      #pragma unroll
      for (int kk = 0; kk < 4; ++kk)
        ao[mt][kk] = *(const bf16x8*)&os[(mt * 16 + m) * XS_STR + kk * 32 + quad * 8];
    float* outb = out + (size_t)blk * (NTOK * CDIM);
    const int n0 = (h * 2 + 0) * 16 + m;
    const int n1 = (h * 2 + 1) * 16 + m;
    f32x4 accD[2][4] = {};
    #pragma unroll
    for (int t = 0; t < 2; ++t) {
      const int n = (h * 2 + t) * 16 + m;
      const short* wr = wp + n * CDIM + quad * 8;
      bf16x8 bw[4];
      #pragma unroll
      for (int kk = 0; kk < 4; ++kk) bw[kk] = *(const bf16x8*)(wr + kk * 32);
      __builtin_amdgcn_s_setprio(1);
      #pragma unroll
      for (int kk = 0; kk < 4; ++kk)
        #pragma unroll
        for (int mt = 0; mt < 4; ++mt)
          accD[t][mt] = MFMA(ao[mt][kk], bw[kk], accD[t][mt]);
      __builtin_amdgcn_s_setprio(0);
    }
    const float pb0 = proj_b[n0];
    const float pb1 = proj_b[n1];
    #pragma unroll
    for (int mt = 0; mt < 4; ++mt)
      #pragma unroll
      for (int r = 0; r < 4; ++r) {
        const int row = mt * 16 + quad * 4 + r;
        if (row < NTOK) {
          outb[row * CDIM + n0] = accD[0][mt][r] + pb0;
          outb[row * CDIM + n1] = accD[1][mt][r] + pb1;
        }
      }
  }
}

extern "C" void kernel_launch(void* const* d_in, const int* in_sizes, int n_in,
                              void* d_out, int out_size, void* d_ws, size_t ws_size,
                              hipStream_t stream)
{
  const float* x          = (const float*)d_in[0];
  const float* mask       = (const float*)d_in[1];
  const float* qkv_w      = (const float*)d_in[2];
  const float* qkv_b      = (const float*)d_in[3];
  const float* proj_w     = (const float*)d_in[4];
  const float* proj_b     = (const float*)d_in[5];
  const float* bias_table = (const float*)d_in[6];

  short* wq = (short*)d_ws;              // 384*128 bf16
  short* wp = wq + 384 * 128;            // 128*128 bf16

  winattn_prep<<<192, 256, 0, stream>>>(qkv_w, proj_w, wq, wp);
  winattn_main<<<8192, 256, LDS_TOTAL, stream>>>(x, mask, qkv_b, proj_b, bias_table,
                                                 wq, wp, (float*)d_out);
}

// Round 5
// 474.909 us; speedup vs baseline: 1.2799x; 1.2174x over previous
//
#include <hip/hip_runtime.h>

typedef short bf16x8 __attribute__((ext_vector_type(8)));
typedef float f32x4  __attribute__((ext_vector_type(4)));
typedef unsigned u32x2 __attribute__((ext_vector_type(2)));

#define MFMA(A, B, C) __builtin_amdgcn_mfma_f32_16x16x32_bf16(A, B, C, 0, 0, 0)

__device__ __forceinline__ short f2b(float f) {
  union { float f; unsigned u; } v; v.f = f;
  unsigned r = v.u + 0x7fffu + ((v.u >> 16) & 1u);   // RNE float->bf16
  return (short)(r >> 16);
}
// packed RNE f32x2 -> bf16x2 (same rounding as f2b, 1 instr per 2 values)
__device__ __forceinline__ unsigned pkbf(float a, float b) {
  unsigned r; asm("v_cvt_pk_bf16_f32 %0, %1, %2" : "=v"(r) : "v"(a), "v"(b));
  return r;
}

#define NTOK 49
#define CDIM 128
#define SCALE 0.17677669529663687f   // 32^-0.5

// ---------------- LDS map (bytes), total 32256 ----------------
// region X [0,13328):
//    t0: xs 49x136 bf16 (x staged)             [freed at B2]
//    t1: msk 49 rows x stride 52 f32 (10192) + bia PER-HEAD 4x176 f32 @10192
//        (per-head contiguous kills the 8-way bank conflict of [idx][h])
//    t2: os 49x136 bf16 (attention output)     [B3..end]
// region V [13328,32256): 4 per-wave slots x 4608 B (wave == head, private):
//    per slot, time-shared: q-scratch 49x40 -> k-scratch 49x40 -> v^T 32x72
//    (v^T pad tokens 49..63 ZEROED at store: PV contracts over keys; 0*NaN leak)
// OCCUPANCY NOTE: 3 blocks/CU by __launch_bounds__(256,3) -> ~170 VGPR/wave.
// At (256,4) the 128-reg budget forced ~280MB/launch of scratch-spill HBM
// write-back (WRITE_SIZE 479MB vs 200MB output) -- spills cost more than the
// 4th resident block bought.
#define XS_STR 136
#define QK_STR 40
#define VT_STR 72
#define MSK_STR 52
#define VOFF    13328
#define SLOT_B  4608
#define BIA_OFF 10192
#define BIA_STR 176
#define LDS_TOTAL 32256

extern "C" __global__ void winattn_prep(const float* __restrict__ qw,
                                        const float* __restrict__ pw,
                                        short* __restrict__ wq, short* __restrict__ wp) {
  const int i = blockIdx.x * 256 + threadIdx.x;
  if (i < 384 * 128) wq[i] = f2b(qw[i]);
  if (i < 128 * 128) wp[i] = f2b(pw[i]);
}

extern "C" __global__ void __launch_bounds__(256, 3)
winattn_main(const float* __restrict__ x, const float* __restrict__ mask,
             const float* __restrict__ qkv_b, const float* __restrict__ proj_b,
             const float* __restrict__ bias_table,
             const short* __restrict__ wq, const short* __restrict__ wp,
             float* __restrict__ out)
{
  extern __shared__ char lds[];
  short* xs  = (short*)lds;
  float* msk = (float*)lds;
  float* bia = (float*)(lds + BIA_OFF);
  short* os  = (short*)lds;

  const int tid  = threadIdx.x;
  const int blk  = blockIdx.x;
  const int wi   = blk & 63;          // window-mask index: b % nW
  const int h    = tid >> 6;          // wave == head
  const int lane = tid & 63;
  const int m    = lane & 15;
  const int quad = lane >> 4;

  short* slot = (short*)(lds + VOFF + h * SLOT_B);   // wave-private

  // ---------------- stage x -> bf16 LDS (stride 136)
  {
    const float4* xg = (const float4*)(x + (size_t)blk * (NTOK * CDIM));
    #pragma unroll
    for (int it = 0; it < 7; ++it) {
      int i = tid + it * 256;
      if (i < NTOK * 32) {
        float4 v = xg[i];
        int row = i >> 5, c4 = (i & 31) << 2;
        u32x2 w; w.x = pkbf(v.x, v.y); w.y = pkbf(v.z, v.w);
        *(u32x2*)&xs[row * XS_STR + c4] = w;
      }
    }
  }
  // mask+bias global loads to registers now (latency hides under barriers/phase A)
  float mreg[10], breg[3];
  {
    const float* mw = mask + (size_t)wi * (NTOK * NTOK);
    #pragma unroll
    for (int it = 0; it < 10; ++it) {
      int i = tid + it * 256;
      mreg[it] = (i < NTOK * NTOK) ? mw[i] : 0.f;
    }
    #pragma unroll
    for (int it = 0; it < 3; ++it) {
      int i = tid + it * 256;
      breg[it] = (i < 169 * 4) ? bias_table[i] : 0.f;
    }
  }
  __syncthreads();                                   // B1: xs ready

  // shared A-fragments of the QKV GEMM (x tile), all waves identical
  bf16x8 ax[4][4];
  #pragma unroll
  for (int mt = 0; mt < 4; ++mt)
    #pragma unroll
    for (int kk = 0; kk < 4; ++kk)
      ax[mt][kk] = *(const bf16x8*)&xs[(mt * 16 + m) * XS_STR + kk * 32 + quad * 8];
  __syncthreads();                                   // B2: xs region free

  // mask (stride 52, float4-readable) + bias (PER-HEAD rows) into region X
  #pragma unroll
  for (int it = 0; it < 10; ++it) {
    int i = tid + it * 256;
    if (i < NTOK * NTOK) {
      int row = (unsigned)i / 49u, col = i - row * 49;
      msk[row * MSK_STR + col] = mreg[it];
    }
  }
  #pragma unroll
  for (int it = 0; it < 3; ++it) {
    int i = tid + it * 256;
    if (i < 169 * 4) bia[(i & 3) * BIA_STR + (i >> 2)] = breg[it];
  }

  // ---------------- phase A: head-aligned qkv tiles (q0 q1 k0 k1 v0 v1)
  // scratch col swizzle: col ^ ((row&8)?8:0) -> store conflicts 4-way -> 2-way
  bf16x8 bq[4], ak[4];
  #pragma unroll
  for (int t = 0; t < 6; ++t) {
    const int kind = t >> 1, sub = t & 1;
    const int n = kind * 128 + h * 32 + sub * 16 + m;
    const short* wr = wq + n * CDIM + quad * 8;
    bf16x8 bw[4];
    #pragma unroll
    for (int kk = 0; kk < 4; ++kk) bw[kk] = *(const bf16x8*)(wr + kk * 32);
    f32x4 acc[4] = {};
    __builtin_amdgcn_s_setprio(1);
    #pragma unroll
    for (int kk = 0; kk < 4; ++kk)
      #pragma unroll
      for (int mt = 0; mt < 4; ++mt)
        acc[mt] = MFMA(ax[mt][kk], bw[kk], acc[mt]);
    __builtin_amdgcn_s_setprio(0);
    const float bb = qkv_b[n];
    if (kind < 2) {
      const int cs = (sub * 16 + m) ^ ((quad >= 2) ? 8 : 0);  // row&8 == (quad>=2)*8
      #pragma unroll
      for (int mt = 0; mt < 4; ++mt)
        #pragma unroll
        for (int j = 0; j < 2; ++j) {
          const int row = mt * 16 + quad * 4 + 2 * j;
          unsigned u = pkbf(acc[mt][2 * j] + bb, acc[mt][2 * j + 1] + bb);
          if (row < NTOK)     slot[row * QK_STR + cs] = (short)u;
          if (row + 1 < NTOK) slot[(row + 1) * QK_STR + cs] = (short)(u >> 16);
        }
    } else {
      // v stored transposed in slot: [channel 0..31][token 0..63], pairs packed.
      // PAD TOKENS (>=49) MUST BE 0.0 (PV contracts over all 64 keys).
      const int c = sub * 16 + m;
      #pragma unroll
      for (int mt = 0; mt < 4; ++mt) {
        const int t0 = mt * 16 + quad * 4;
        const float e0 = (t0 + 0 < NTOK) ? acc[mt][0] + bb : 0.f;
        const float e1 = (t0 + 1 < NTOK) ? acc[mt][1] + bb : 0.f;
        const float e2 = (t0 + 2 < NTOK) ? acc[mt][2] + bb : 0.f;
        const float e3 = (t0 + 3 < NTOK) ? acc[mt][3] + bb : 0.f;
        u32x2 w;
        w.x = pkbf(e0, e1);
        w.y = pkbf(e2, e3);
        *(u32x2*)&slot[c * VT_STR + t0] = w;
      }
    }
    if (t == 1) {          // q done -> B-fragments (queries); same-wave DS is FIFO
      #pragma unroll
      for (int qt = 0; qt < 4; ++qt)
        bq[qt] = *(const bf16x8*)&slot[(qt * 16 + m) * QK_STR + ((quad * 8) ^ (m & 8))];
    }
    if (t == 3) {          // k done -> A-fragments (keys)
      #pragma unroll
      for (int kt = 0; kt < 4; ++kt)
        ak[kt] = *(const bf16x8*)&slot[(kt * 16 + m) * QK_STR + ((quad * 8) ^ (m & 8))];
    }
  }

  // ---------------- phase B: S^T = K Q^T  (rows=keys, cols=queries), K=32
  f32x4 st[4][4] = {};
  __builtin_amdgcn_s_setprio(1);
  #pragma unroll
  for (int kt = 0; kt < 4; ++kt)
    #pragma unroll
    for (int qt = 0; qt < 4; ++qt)
      st[kt][qt] = MFMA(ak[kt], bq[qt], st[kt][qt]);
  __builtin_amdgcn_s_setprio(0);

  __syncthreads();                                   // Bm: msk/bia visible

  // ---------------- softmax over keys (column-wise on S^T): quad-local reduce
  int kc[13];
  #pragma unroll
  for (int i = 0; i < 13; ++i) {                     // kt<3 all r, plus (kt=3,r=0)
    int kt = i >> 2, r = i & 3;
    int key = kt * 16 + quad * 4 + r;
    int ch = (unsigned)key / 7u;
    kc[i] = ch * 13 + (key - ch * 7);
  }
  const float* biah = bia + h * BIA_STR;
  float rinv[4];
  #pragma unroll
  for (int qt = 0; qt < 4; ++qt) {
    const int query = qt * 16 + m;
    const int rh = (unsigned)query / 7u;
    const int qcode = rh * 13 + (query - rh * 7) + 84;   // idx = qcode - kcode
    float sv[13];
    #pragma unroll
    for (int kt = 0; kt < 3; ++kt) {
      const float4 mk = *(const float4*)&msk[query * MSK_STR + kt * 16 + quad * 4];
      #pragma unroll
      for (int r = 0; r < 4; ++r) {
        const float b = biah[qcode - kc[kt * 4 + r]];
        sv[kt * 4 + r] = st[kt][qt][r] * SCALE + ((const float*)&mk)[r] + b;
      }
    }
    {   // kt=3: only key 48 (quad==0, r==0) is real
      const float mk3 = msk[query * MSK_STR + 48];
      const float b3 = biah[qcode - kc[12]];
      float s = st[3][qt][0] * SCALE + mk3 + b3;
      sv[12] = (quad == 0) ? s : -1e30f;
    }
    float mx = sv[0];
    #pragma unroll
    for (int i = 1; i < 13; ++i) mx = fmaxf(mx, sv[i]);
    mx = fmaxf(mx, __shfl_xor(mx, 16));
    mx = fmaxf(mx, __shfl_xor(mx, 32));
    float sum = 0.f;
    #pragma unroll
    for (int i = 0; i < 13; ++i) {
      const float p = __expf(sv[i] - mx);             // unnormalized, 1/sum into O
      sum += p;
      st[i >> 2][qt][i & 3] = p;
    }
    st[3][qt][1] = 0.f; st[3][qt][2] = 0.f; st[3][qt][3] = 0.f;  // pad keys
    sum += __shfl_xor(sum, 16);
    sum += __shfl_xor(sum, 32);
    rinv[qt] = 1.f / sum;
  }

  // ---------------- phase C: O^T = V^T P^T, P^T B-frags via ds_bpermute dance
  bf16x8 av[2][2];
  #pragma unroll
  for (int ct = 0; ct < 2; ++ct)
    #pragma unroll
    for (int k2 = 0; k2 < 2; ++k2)
      av[ct][k2] = *(const bf16x8*)&slot[(ct * 16 + m) * VT_STR + k2 * 32 + quad * 8];

  // fixed 64-lane permutation addresses (byte = lane*4)
  const int A0  = (lane ^ ((quad & 1) ? 48 : 0))  << 2;
  const int B0  = (lane ^ ((quad & 1) ? 16 : 32)) << 2;
  const int A2  = (lane ^ ((quad & 1) ? 32 : 16)) << 2;
  const int B2g = (lane ^ ((quad & 1) ? 0 : 48))  << 2;
  const bool qlo = quad < 2;

  f32x4 oacc[2][4] = {};
  #pragma unroll
  for (int qt = 0; qt < 4; ++qt) {
    #pragma unroll
    for (int k2 = 0; k2 < 2; ++k2) {
      const unsigned elo = pkbf(st[2 * k2][qt][0], st[2 * k2][qt][1]);
      const unsigned ehi = pkbf(st[2 * k2][qt][2], st[2 * k2][qt][3]);
      const unsigned olo = pkbf(st[2 * k2 + 1][qt][0], st[2 * k2 + 1][qt][1]);
      const unsigned ohi = pkbf(st[2 * k2 + 1][qt][2], st[2 * k2 + 1][qt][3]);
      // bpermutes unconditional (convergent, full exec), then per-lane select
      const unsigned p0e = __builtin_amdgcn_ds_bpermute(A0,  (int)elo);
      const unsigned p0o = __builtin_amdgcn_ds_bpermute(B0,  (int)olo);
      const unsigned p1e = __builtin_amdgcn_ds_bpermute(A0,  (int)ehi);
      const unsigned p1o = __builtin_amdgcn_ds_bpermute(B0,  (int)ohi);
      const unsigned p2e = __builtin_amdgcn_ds_bpermute(A2,  (int)elo);
      const unsigned p2o = __builtin_amdgcn_ds_bpermute(B2g, (int)olo);
      const unsigned p3e = __builtin_amdgcn_ds_bpermute(A2,  (int)ehi);
      const unsigned p3o = __builtin_amdgcn_ds_bpermute(B2g, (int)ohi);
      union { unsigned u[4]; bf16x8 v; } pb;
      pb.u[0] = qlo ? p0e : p0o;
      pb.u[1] = qlo ? p1e : p1o;
      pb.u[2] = qlo ? p2e : p2o;
      pb.u[3] = qlo ? p3e : p3o;
      __builtin_amdgcn_s_setprio(1);
      #pragma unroll
      for (int ct = 0; ct < 2; ++ct)
        oacc[ct][qt] = MFMA(av[ct][k2], pb.v, oacc[ct][qt]);
      __builtin_amdgcn_s_setprio(0);
    }
  }

  __syncthreads();     // B3: all mask/bias reads done -> os may overwrite region X
  #pragma unroll
  for (int ct = 0; ct < 2; ++ct)
    #pragma unroll
    for (int qt = 0; qt < 4; ++qt) {
      const int query = qt * 16 + m;
      if (query < NTOK) {
        u32x2 w;
        w.x = pkbf(oacc[ct][qt][0] * rinv[qt], oacc[ct][qt][1] * rinv[qt]);
        w.y = pkbf(oacc[ct][qt][2] * rinv[qt], oacc[ct][qt][3] * rinv[qt]);
        *(u32x2*)&os[query * XS_STR + h * 32 + ct * 16 + quad * 4] = w;
      }
    }
  __syncthreads();                                   // B4: os ready

  // ---------------- phase D: out = O @ proj_w^T + proj_b, fp32 store
  // Both n-tiles computed first, stores per row back-to-back (full 128B line).
  {
    bf16x8 ao[4][4];
    #pragma unroll
    for (int mt = 0; mt < 4; ++mt)
      #pragma unroll
      for (int kk = 0; kk < 4; ++kk)
        ao[mt][kk] = *(const bf16x8*)&os[(mt * 16 + m) * XS_STR + kk * 32 + quad * 8];
    float* outb = out + (size_t)blk * (NTOK * CDIM);
    const int n0 = (h * 2 + 0) * 16 + m;
    const int n1 = (h * 2 + 1) * 16 + m;
    f32x4 accD[2][4] = {};
    #pragma unroll
    for (int t = 0; t < 2; ++t) {
      const int n = (h * 2 + t) * 16 + m;
      const short* wr = wp + n * CDIM + quad * 8;
      bf16x8 bw[4];
      #pragma unroll
      for (int kk = 0; kk < 4; ++kk) bw[kk] = *(const bf16x8*)(wr + kk * 32);
      __builtin_amdgcn_s_setprio(1);
      #pragma unroll
      for (int kk = 0; kk < 4; ++kk)
        #pragma unroll
        for (int mt = 0; mt < 4; ++mt)
          accD[t][mt] = MFMA(ao[mt][kk], bw[kk], accD[t][mt]);
      __builtin_amdgcn_s_setprio(0);
    }
    const float pb0 = proj_b[n0];
    const float pb1 = proj_b[n1];
    #pragma unroll
    for (int mt = 0; mt < 4; ++mt)
      #pragma unroll
      for (int r = 0; r < 4; ++r) {
        const int row = mt * 16 + quad * 4 + r;
        if (row < NTOK) {
          outb[row * CDIM + n0] = accD[0][mt][r] + pb0;
          outb[row * CDIM + n1] = accD[1][mt][r] + pb1;
        }
      }
  }
}

extern "C" void kernel_launch(void* const* d_in, const int* in_sizes, int n_in,
                              void* d_out, int out_size, void* d_ws, size_t ws_size,
                              hipStream_t stream)
{
  const float* x          = (const float*)d_in[0];
  const float* mask       = (const float*)d_in[1];
  const float* qkv_w      = (const float*)d_in[2];
  const float* qkv_b      = (const float*)d_in[3];
  const float* proj_w     = (const float*)d_in[4];
  const float* proj_b     = (const float*)d_in[5];
  const float* bias_table = (const float*)d_in[6];

  short* wq = (short*)d_ws;              // 384*128 bf16
  short* wp = wq + 384 * 128;            // 128*128 bf16

  winattn_prep<<<192, 256, 0, stream>>>(qkv_w, proj_w, wq, wp);
  winattn_main<<<8192, 256, LDS_TOTAL, stream>>>(x, mask, qkv_b, proj_b, bias_table,
                                                 wq, wp, (float*)d_out);
}